// Round 6
// baseline (811.478 us; speedup 1.0000x reference)
//
#include <hip/hip_runtime.h>
#include <hip/hip_bf16.h>

// LSTM: B=16384, T=200, IN=9, H=64, OUT=3, 2 layers + linear head.
// Round 6: LUT activations. R4 structure (4 waves/block, 16 batches) +
//   sigmoid/tanh via 1024-entry (value,delta) f32 LERP tables in LDS.
//   Table coordinate transform folded into packed weights/biases:
//     i,f,o rows: W*32, bias*32+512  -> u = 32x+512, sigma table on [-16,16)
//     g rows:     W*64, bias*64+512  -> u = 64g+512, tanh  table on [-8,8)
//     tanh(c): u = fma(c,64,512) at runtime.
//   Eliminates all v_exp/v_rcp (was ~75-80% of VALUBusy).
//   x: per-lane register prefetch (xwin LDS deleted).
// Fragment layouts (gfx950 16x16x32, verified R2-R5):
//   A: lane l holds A[m=l&15][k=4*(l>>4)+(j&3)+16*(j>>2)]
//   B: lane l holds B[k=...][n=l&15]
//   C/D: col=l&15, row=(l>>4)*4+reg
// LDS h-state k-PERMUTED (R3): k=c*32+4q+s -> pos=c*32+8q+s ; k+16 -> pos+4

#define B_TOT   16384
#define T_STEPS 200
#define IN_DIM  9
#define HDIM    64

// ws layout: f16 weights, then f32 biases, then float2 tables
#define PK1_OFF 0         // [3][16][64][8] = 24576 f16
#define PK2_OFF 24576     // [4][16][64][8] = 32768 f16
#define PACK_W_TOT 57344              // f16 units
#define BSUM_HALF_OFF 57344           // 512 f32 after this (f16-unit offset)
#define PACK_TOT (PACK_W_TOT + 512)   // "e" units for weight+bias part
#define TAB_BYTE_OFF (57344*2 + 512*4)   // 116736: sig[1024]float2, tanh[1024]float2
#define N_TAB_E 2048                  // table-entry threads

typedef _Float16 half8 __attribute__((ext_vector_type(8)));
typedef float    f32x4 __attribute__((ext_vector_type(4)));
typedef float    f4u   __attribute__((ext_vector_type(4), aligned(4)));

// ---------------- prep: repack weights + build LUTs ----------------
__global__ void pack_kernel(const float* __restrict__ Wih1, const float* __restrict__ Whh1,
                            const float* __restrict__ bih1, const float* __restrict__ bhh1,
                            const float* __restrict__ Wih2, const float* __restrict__ Whh2,
                            const float* __restrict__ bih2, const float* __restrict__ bhh2,
                            float* __restrict__ ws) {
    int e = blockIdx.x * 256 + threadIdx.x;
    if (e >= PACK_TOT + N_TAB_E) return;
    _Float16* wh = (_Float16*)ws;
    float* bptr = (float*)(wh + BSUM_HALF_OFF);
    float2* sigt = (float2*)((char*)ws + TAB_BYTE_OFF);
    float2* tant = sigt + 1024;
    auto gscale = [](int q) -> float {       // table-coordinate scale per gate row
        return ((q >> 6) == 2) ? 64.0f : 32.0f;
    };
    if (e < PK2_OFF) {
        int j = e & 7, lane = (e >> 3) & 63, nt = (e >> 9) & 15, c = e >> 13;
        int k = c * 32 + 4 * (lane >> 4) + (j & 3) + 16 * (j >> 2);
        int q = nt * 16 + (lane & 15);
        float v = 0.0f;
        if (k < 64)      v = Whh1[q * 64 + k];
        else if (k < 73) v = Wih1[q * 9 + (k - 64)];
        wh[e] = (_Float16)(v * gscale(q));
    } else if (e < PACK_W_TOT) {
        int e2 = e - PK2_OFF;
        int j = e2 & 7, lane = (e2 >> 3) & 63, nt = (e2 >> 9) & 15, c = e2 >> 13;
        int k = c * 32 + 4 * (lane >> 4) + (j & 3) + 16 * (j >> 2);
        int q = nt * 16 + (lane & 15);
        float v = (k < 64) ? Wih2[q * 64 + k] : Whh2[q * 64 + (k - 64)];
        wh[e] = (_Float16)(v * gscale(q));
    } else if (e < PACK_W_TOT + 256) {
        int q = e - PACK_W_TOT;
        bptr[q] = (bih1[q] + bhh1[q]) * gscale(q) + 512.0f;
    } else if (e < PACK_TOT) {
        int q = e - PACK_W_TOT - 256;
        bptr[256 + q] = (bih2[q] + bhh2[q]) * gscale(q) + 512.0f;
    } else {
        int j = e - PACK_TOT;
        if (j < 1024) {            // sigma: entry j <-> x = (j-512)/32
            float x0 = (j - 512) * (1.0f / 32.0f);
            float x1 = (j - 511) * (1.0f / 32.0f);
            float a = 1.0f / (1.0f + __expf(-x0));
            float b = 1.0f / (1.0f + __expf(-x1));
            sigt[j] = make_float2(a, b - a);
        } else {                   // tanh: entry j <-> y = (j-512)/64
            int j2 = j - 1024;
            float y0 = (j2 - 512) * (1.0f / 64.0f);
            float y1 = (j2 - 511) * (1.0f / 64.0f);
            float a = tanhf(y0);
            float b = tanhf(y1);
            tant[j2] = make_float2(a, b - a);
        }
    }
}

// ---------------- main sequential LSTM (MFMA + LUT) ----------------
__global__ __launch_bounds__(256, 1) void lstm_mfma(
    const float* __restrict__ x,
    const float* __restrict__ ws_f,
    const float* __restrict__ Wout,
    const float* __restrict__ bout,
    float* __restrict__ out)
{
    const int tid  = threadIdx.x;
    const int lane = tid & 63;
    const int w    = __builtin_amdgcn_readfirstlane(tid >> 6);   // 0..3
    const int l15  = lane & 15;
    const int l4   = lane >> 4;

    const _Float16* wh  = (const _Float16*)ws_f;
    const _Float16* pk1 = wh + PK1_OFF;
    const _Float16* pk2 = wh + PK2_OFF;
    const float* bsum   = (const float*)(wh + BSUM_HALF_OFF);

    __shared__ _Float16 h1s[2][16][72];
    __shared__ _Float16 h2s[2][16][72];
    __shared__ float2 sigt[1024];
    __shared__ float2 tant[1024];

    // copy LUTs global->LDS (16KB)
    {
        const float2* gsig = (const float2*)((const char*)ws_f + TAB_BYTE_OFF);
        for (int i = tid; i < 1024; i += 256) {
            sigt[i] = gsig[i];
            tant[i] = gsig[1024 + i];
        }
    }
    for (int i = tid; i < 2 * 16 * 72; i += 256) {
        (&h1s[0][0][0])[i] = (_Float16)0.0f;
        (&h2s[0][0][0])[i] = (_Float16)0.0f;
    }

    const int bbase = blockIdx.x * 16;
    const float* xb = x + (long)(bbase + l15) * (T_STEPS * IN_DIM);

    // x prefetch regs: step-0 values (lane l15 = batch; l4 selects k-quad)
    f4u  cx  = {0.f, 0.f, 0.f, 0.f};
    float cx8 = 0.0f;
    if (l4 < 2)       cx  = *(const f4u*)(xb + 4 * l4);
    else if (l4 == 2) cx8 = xb[8];

    // ---- load B fragments (weights): 28 x half8 = 112 regs
    half8 bw1_00, bw1_01, bw1_02, bw1_03;
    half8 bw1_10, bw1_11, bw1_12, bw1_13;
    half8 bw1_20, bw1_21, bw1_22, bw1_23;
    half8 bw2_00, bw2_01, bw2_02, bw2_03;
    half8 bw2_10, bw2_11, bw2_12, bw2_13;
    half8 bw2_20, bw2_21, bw2_22, bw2_23;
    half8 bw2_30, bw2_31, bw2_32, bw2_33;
    {
        #define LD1(c,g) *(const half8*)(pk1 + (((c * 16) + (w + 4 * g)) * 64 + lane) * 8)
        #define LD2(c,g) *(const half8*)(pk2 + (((c * 16) + (w + 4 * g)) * 64 + lane) * 8)
        bw1_00 = LD1(0,0); bw1_01 = LD1(0,1); bw1_02 = LD1(0,2); bw1_03 = LD1(0,3);
        bw1_10 = LD1(1,0); bw1_11 = LD1(1,1); bw1_12 = LD1(1,2); bw1_13 = LD1(1,3);
        bw1_20 = LD1(2,0); bw1_21 = LD1(2,1); bw1_22 = LD1(2,2); bw1_23 = LD1(2,3);
        bw2_00 = LD2(0,0); bw2_01 = LD2(0,1); bw2_02 = LD2(0,2); bw2_03 = LD2(0,3);
        bw2_10 = LD2(1,0); bw2_11 = LD2(1,1); bw2_12 = LD2(1,2); bw2_13 = LD2(1,3);
        bw2_20 = LD2(2,0); bw2_21 = LD2(2,1); bw2_22 = LD2(2,2); bw2_23 = LD2(2,3);
        bw2_30 = LD2(3,0); bw2_31 = LD2(3,1); bw2_32 = LD2(3,2); bw2_33 = LD2(3,3);
        #undef LD1
        #undef LD2
    }

    float bias1[4], bias2[4];
    #pragma unroll
    for (int g = 0; g < 4; ++g) {
        bias1[g] = bsum[(w + 4 * g) * 16 + l15];
        bias2[g] = bsum[256 + (w + 4 * g) * 16 + l15];
    }

    const int hpos = ((w >> 1) << 5) + 8 * (l15 >> 2) + (l15 & 3) + ((w & 1) << 2);

    f32x4 c1 = {0.f, 0.f, 0.f, 0.f};
    f32x4 c2 = {0.f, 0.f, 0.f, 0.f};

    // LERP lookup: u is the table coordinate (already scaled+offset)
    auto lut = [&](const float2* t, float u) -> float {
        float uc = __builtin_fminf(__builtin_fmaxf(u, 0.0f), 1022.999f);
        int idx = (int)uc;
        float fr = uc - (float)idx;
        float2 en = t[idx];
        return __builtin_fmaf(fr, en.y, en.x);
    };

    __syncthreads();   // LUTs + zero h state visible

    int p = 0;
    for (int t = 0; t < T_STEPS; ++t) {
        // pin weight frags: loop-carried in regs, no remat-by-reload
        asm volatile("" :
            "+v"(bw1_00), "+v"(bw1_01), "+v"(bw1_02), "+v"(bw1_03),
            "+v"(bw1_10), "+v"(bw1_11), "+v"(bw1_12), "+v"(bw1_13),
            "+v"(bw1_20), "+v"(bw1_21), "+v"(bw1_22), "+v"(bw1_23));
        asm volatile("" :
            "+v"(bw2_00), "+v"(bw2_01), "+v"(bw2_02), "+v"(bw2_03),
            "+v"(bw2_10), "+v"(bw2_11), "+v"(bw2_12), "+v"(bw2_13),
            "+v"(bw2_20), "+v"(bw2_21), "+v"(bw2_22), "+v"(bw2_23),
            "+v"(bw2_30), "+v"(bw2_31), "+v"(bw2_32), "+v"(bw2_33));

        // ---- build x A-frag from prefetched regs; prefetch next step
        half8 ax;
        {
            float e0 = (l4 == 2) ? cx8 : cx[0];
            ax[0] = (_Float16)e0;    ax[1] = (_Float16)cx[1];
            ax[2] = (_Float16)cx[2]; ax[3] = (_Float16)cx[3];
            ax[4] = ax[5] = ax[6] = ax[7] = (_Float16)0.0f;
            if (t + 1 < T_STEPS) {
                const float* xp = xb + (t + 1) * IN_DIM;
                if (l4 < 2)       cx  = *(const f4u*)(xp + 4 * l4);
                else if (l4 == 2) cx8 = xp[8];
            }
        }

        // ---- old-state A-fragments
        half8 a1c0 = *(const half8*)&h1s[p][l15][ 0 + 8 * l4];
        half8 a1c1 = *(const half8*)&h1s[p][l15][32 + 8 * l4];
        half8 a2h0 = *(const half8*)&h2s[p][l15][ 0 + 8 * l4];
        half8 a2h1 = *(const half8*)&h2s[p][l15][32 + 8 * l4];

        // ---- layer1 MFMA
        f32x4 C[4];
        #pragma unroll
        for (int g = 0; g < 4; ++g) C[g] = (f32x4){bias1[g], bias1[g], bias1[g], bias1[g]};
        C[0] = __builtin_amdgcn_mfma_f32_16x16x32_f16(a1c0, bw1_00, C[0], 0, 0, 0);
        C[1] = __builtin_amdgcn_mfma_f32_16x16x32_f16(a1c0, bw1_01, C[1], 0, 0, 0);
        C[2] = __builtin_amdgcn_mfma_f32_16x16x32_f16(a1c0, bw1_02, C[2], 0, 0, 0);
        C[3] = __builtin_amdgcn_mfma_f32_16x16x32_f16(a1c0, bw1_03, C[3], 0, 0, 0);
        C[0] = __builtin_amdgcn_mfma_f32_16x16x32_f16(a1c1, bw1_10, C[0], 0, 0, 0);
        C[1] = __builtin_amdgcn_mfma_f32_16x16x32_f16(a1c1, bw1_11, C[1], 0, 0, 0);
        C[2] = __builtin_amdgcn_mfma_f32_16x16x32_f16(a1c1, bw1_12, C[2], 0, 0, 0);
        C[3] = __builtin_amdgcn_mfma_f32_16x16x32_f16(a1c1, bw1_13, C[3], 0, 0, 0);
        C[0] = __builtin_amdgcn_mfma_f32_16x16x32_f16(ax,   bw1_20, C[0], 0, 0, 0);
        C[1] = __builtin_amdgcn_mfma_f32_16x16x32_f16(ax,   bw1_21, C[1], 0, 0, 0);
        C[2] = __builtin_amdgcn_mfma_f32_16x16x32_f16(ax,   bw1_22, C[2], 0, 0, 0);
        C[3] = __builtin_amdgcn_mfma_f32_16x16x32_f16(ax,   bw1_23, C[3], 0, 0, 0);

        // ---- layer2 partial MFMA (h2_old)
        f32x4 D[4];
        #pragma unroll
        for (int g = 0; g < 4; ++g) D[g] = (f32x4){bias2[g], bias2[g], bias2[g], bias2[g]};
        D[0] = __builtin_amdgcn_mfma_f32_16x16x32_f16(a2h0, bw2_20, D[0], 0, 0, 0);
        D[1] = __builtin_amdgcn_mfma_f32_16x16x32_f16(a2h0, bw2_21, D[1], 0, 0, 0);
        D[2] = __builtin_amdgcn_mfma_f32_16x16x32_f16(a2h0, bw2_22, D[2], 0, 0, 0);
        D[3] = __builtin_amdgcn_mfma_f32_16x16x32_f16(a2h0, bw2_23, D[3], 0, 0, 0);
        D[0] = __builtin_amdgcn_mfma_f32_16x16x32_f16(a2h1, bw2_30, D[0], 0, 0, 0);
        D[1] = __builtin_amdgcn_mfma_f32_16x16x32_f16(a2h1, bw2_31, D[1], 0, 0, 0);
        D[2] = __builtin_amdgcn_mfma_f32_16x16x32_f16(a2h1, bw2_32, D[2], 0, 0, 0);
        D[3] = __builtin_amdgcn_mfma_f32_16x16x32_f16(a2h1, bw2_33, D[3], 0, 0, 0);

        // ---- layer1 cell update via LUT
        #pragma unroll
        for (int r = 0; r < 4; ++r) {
            float ig = lut(sigt, C[0][r]);
            float fg = lut(sigt, C[1][r]);
            float gg = lut(tant, C[2][r]);
            float og = lut(sigt, C[3][r]);
            float cc = __builtin_fmaf(fg, c1[r], ig * gg);
            c1[r] = cc;
            float th = lut(tant, __builtin_fmaf(cc, 64.0f, 512.0f));
            h1s[1 - p][4 * l4 + r][hpos] = (_Float16)(og * th);
        }
        __syncthreads();           // B_a: h1_new visible

        // ---- finish layer2 with h1_new
        half8 a20 = *(const half8*)&h1s[1 - p][l15][ 0 + 8 * l4];
        half8 a21 = *(const half8*)&h1s[1 - p][l15][32 + 8 * l4];
        D[0] = __builtin_amdgcn_mfma_f32_16x16x32_f16(a20, bw2_00, D[0], 0, 0, 0);
        D[1] = __builtin_amdgcn_mfma_f32_16x16x32_f16(a20, bw2_01, D[1], 0, 0, 0);
        D[2] = __builtin_amdgcn_mfma_f32_16x16x32_f16(a20, bw2_02, D[2], 0, 0, 0);
        D[3] = __builtin_amdgcn_mfma_f32_16x16x32_f16(a20, bw2_03, D[3], 0, 0, 0);
        D[0] = __builtin_amdgcn_mfma_f32_16x16x32_f16(a21, bw2_10, D[0], 0, 0, 0);
        D[1] = __builtin_amdgcn_mfma_f32_16x16x32_f16(a21, bw2_11, D[1], 0, 0, 0);
        D[2] = __builtin_amdgcn_mfma_f32_16x16x32_f16(a21, bw2_12, D[2], 0, 0, 0);
        D[3] = __builtin_amdgcn_mfma_f32_16x16x32_f16(a21, bw2_13, D[3], 0, 0, 0);

        // ---- layer2 cell update via LUT
        #pragma unroll
        for (int r = 0; r < 4; ++r) {
            float ig = lut(sigt, D[0][r]);
            float fg = lut(sigt, D[1][r]);
            float gg = lut(tant, D[2][r]);
            float og = lut(sigt, D[3][r]);
            float cc = __builtin_fmaf(fg, c2[r], ig * gg);
            c2[r] = cc;
            float th = lut(tant, __builtin_fmaf(cc, 64.0f, 512.0f));
            h2s[1 - p][4 * l4 + r][hpos] = (_Float16)(og * th);
        }
        __syncthreads();           // B_b: h2_new visible
        p ^= 1;
    }

    // ---- output head (h2s perm-stored; p == 0 after 200 flips)
    if (tid < 48) {
        int bl = tid / 3, o = tid - bl * 3;
        float acc = bout[o];
        #pragma unroll 8
        for (int pos = 0; pos < HDIM; ++pos) {
            int sub = pos & 31;
            int j = (pos >> 5) * 32 + (((sub >> 2) & 1) << 4) + ((sub >> 3) << 2) + (sub & 3);
            acc = __builtin_fmaf(Wout[o * 64 + j], (float)h2s[0][bl][pos], acc);
        }
        out[(bbase + bl) * 3 + o] = acc;
    }
}

extern "C" void kernel_launch(void* const* d_in, const int* in_sizes, int n_in,
                              void* d_out, int out_size, void* d_ws, size_t ws_size,
                              hipStream_t stream) {
    const float* x     = (const float*)d_in[0];
    const float* Wih1  = (const float*)d_in[1];
    const float* Whh1  = (const float*)d_in[2];
    const float* bih1  = (const float*)d_in[3];
    const float* bhh1  = (const float*)d_in[4];
    const float* Wih2  = (const float*)d_in[5];
    const float* Whh2  = (const float*)d_in[6];
    const float* bih2  = (const float*)d_in[7];
    const float* bhh2  = (const float*)d_in[8];
    const float* Wout  = (const float*)d_in[9];
    const float* bout  = (const float*)d_in[10];
    float* ws  = (float*)d_ws;
    float* out = (float*)d_out;

    pack_kernel<<<(PACK_TOT + N_TAB_E + 255) / 256, 256, 0, stream>>>(
        Wih1, Whh1, bih1, bhh1, Wih2, Whh2, bih2, bhh2, ws);

    lstm_mfma<<<B_TOT / 16, 256, 0, stream>>>(x, ws, Wout, bout, out);
}

// Round 7
// 597.381 us; speedup vs baseline: 1.3584x; 1.3584x over previous
//
#include <hip/hip_runtime.h>
#include <hip/hip_bf16.h>

// LSTM: B=16384, T=200, IN=9, H=64, OUT=3, 2 layers + linear head.
// Round 7: merged-reciprocal activations (7 trans/cell, was 10) +
//          single-barrier-per-step pipeline (was 2), h1-frag reuse.
// Block = 16 batches, 256 threads (4 waves). Grid = 1024 blocks.
// Wave w owns gate n-tiles {w, w+4, w+8, w+12}.
// Fragment layouts (gfx950 16x16x32, verified R2-R6):
//   A: lane l holds A[m=l&15][k=4*(l>>4)+(j&3)+16*(j>>2)]
//   B: lane l holds B[k=...][n=l&15]
//   C/D: col=l&15, row=(l>>4)*4+reg
// LDS h-state k-PERMUTED (R3): k=c*32+4q+s -> pos=c*32+8q+s ; k+16 -> pos+4
// Weight pre-scale: i,f,o rows x(-log2e); g rows x(-2*log2e)  [NOTE sign!]
//   e_i=exp2(Ci)=e^-xi, e_g=exp2(Cg)=e^-2g
//   c' = [c*ai*ag + (1-eg)*af] * rcp(af*ai*ag)      (1 rcp for f*c+i*tanh(g))
//   h  = sign(c')*(1-ec)*rcp(ao*(1+ec)), ec=exp2(-2L2E*|c'|)  (overflow-safe)
// Pipeline per step (ONE barrier):
//   1. L1 cell-update from C(t) -> write h1(t) [buf 1-p]
//   2. __syncthreads
//   3. read h1(t), h2(t-1) frags; build ax=x(t+1); prefetch x(t+2)
//   4. D = gates2(t) MFMA;  C' = gates1(t+1) MFMA (h1 frags shared)
//   5. L2 cell-update from D -> write h2(t) [buf 1-p]
//   6. C = C'; p ^= 1
// Race check: h-buffers double-buffered; every write->read pair of the same
// buffer is separated by the collective barrier of the consuming iteration.

#define B_TOT   16384
#define T_STEPS 200
#define IN_DIM  9
#define HDIM    64

#define PK1_OFF 0         // [3][16][64][8] = 24576 f16
#define PK2_OFF 24576     // [4][16][64][8] = 32768 f16
#define BSUM_HALF_OFF 57344   // then 512 f32 (b1[256], b2[256])
#define PACK_W_TOT 57344
#define PACK_TOT (PACK_W_TOT + 512)

#define L2E     1.44269504089f
#define TWOL2E  2.88539008178f

typedef _Float16 half8 __attribute__((ext_vector_type(8)));
typedef float    f32x4 __attribute__((ext_vector_type(4)));
typedef float    f4u   __attribute__((ext_vector_type(4), aligned(4)));

// ---------------- prep: repack weights (B-frag layout, scales folded) -------
__global__ void pack_kernel(const float* __restrict__ Wih1, const float* __restrict__ Whh1,
                            const float* __restrict__ bih1, const float* __restrict__ bhh1,
                            const float* __restrict__ Wih2, const float* __restrict__ Whh2,
                            const float* __restrict__ bih2, const float* __restrict__ bhh2,
                            float* __restrict__ ws) {
    int e = blockIdx.x * 256 + threadIdx.x;
    if (e >= PACK_TOT) return;
    _Float16* wh = (_Float16*)ws;
    float* bptr = (float*)(wh + BSUM_HALF_OFF);
    auto gscale = [](int q) -> float {
        int gt = q >> 6;                       // 0=i,1=f,2=g,3=o
        return (gt == 2) ? (-2.0f * L2E) : -L2E;
    };
    if (e < PK2_OFF) {
        int j = e & 7, lane = (e >> 3) & 63, nt = (e >> 9) & 15, c = e >> 13;
        int k = c * 32 + 4 * (lane >> 4) + (j & 3) + 16 * (j >> 2);
        int q = nt * 16 + (lane & 15);
        float v = 0.0f;
        if (k < 64)      v = Whh1[q * 64 + k];
        else if (k < 73) v = Wih1[q * 9 + (k - 64)];
        wh[e] = (_Float16)(v * gscale(q));
    } else if (e < PACK_W_TOT) {
        int e2 = e - PK2_OFF;
        int j = e2 & 7, lane = (e2 >> 3) & 63, nt = (e2 >> 9) & 15, c = e2 >> 13;
        int k = c * 32 + 4 * (lane >> 4) + (j & 3) + 16 * (j >> 2);
        int q = nt * 16 + (lane & 15);
        float v = (k < 64) ? Wih2[q * 64 + k] : Whh2[q * 64 + (k - 64)];
        wh[e] = (_Float16)(v * gscale(q));
    } else if (e < PACK_W_TOT + 256) {
        int q = e - PACK_W_TOT;
        bptr[q] = (bih1[q] + bhh1[q]) * gscale(q);
    } else {
        int q = e - PACK_W_TOT - 256;
        bptr[256 + q] = (bih2[q] + bhh2[q]) * gscale(q);
    }
}

// ---------------- main sequential LSTM ----------------
__global__ __launch_bounds__(256, 2) void lstm_mfma(
    const float* __restrict__ x,
    const float* __restrict__ ws_f,
    const float* __restrict__ Wout,
    const float* __restrict__ bout,
    float* __restrict__ out)
{
    const int tid  = threadIdx.x;
    const int lane = tid & 63;
    const int w    = __builtin_amdgcn_readfirstlane(tid >> 6);   // 0..3
    const int l15  = lane & 15;
    const int l4   = lane >> 4;

    const _Float16* wh  = (const _Float16*)ws_f;
    const _Float16* pk1 = wh + PK1_OFF;
    const _Float16* pk2 = wh + PK2_OFF;
    const float* bsum   = (const float*)(wh + BSUM_HALF_OFF);

    __shared__ _Float16 h1s[2][16][72];
    __shared__ _Float16 h2s[2][16][72];

    for (int i = tid; i < 2 * 16 * 72; i += 256) {
        (&h1s[0][0][0])[i] = (_Float16)0.0f;
        (&h2s[0][0][0])[i] = (_Float16)0.0f;
    }
    __syncthreads();   // zeros committed before any h write/read

    const int bbase = blockIdx.x * 16;
    const float* xb = x + (long)(bbase + l15) * (T_STEPS * IN_DIM);

    // x prefetch regs (lane l15 = batch, l4 selects k-quad; l4==3 stays 0)
    f4u  cx  = {0.f, 0.f, 0.f, 0.f};
    float cx8 = 0.0f;
    auto prefetch_x = [&](int tt) {
        const float* xp = xb + tt * IN_DIM;
        if (l4 < 2)       cx  = *(const f4u*)(xp + 4 * l4);
        else if (l4 == 2) cx8 = xp[8];
    };
    auto build_ax = [&]() -> half8 {
        half8 ax;
        float e0 = (l4 == 2) ? cx8 : cx[0];
        ax[0] = (_Float16)e0;    ax[1] = (_Float16)cx[1];
        ax[2] = (_Float16)cx[2]; ax[3] = (_Float16)cx[3];
        ax[4] = ax[5] = ax[6] = ax[7] = (_Float16)0.0f;
        return ax;
    };

    // ---- weight B-fragments: 28 x half8 = 112 regs, loop-pinned
    half8 bw1_00, bw1_01, bw1_02, bw1_03;
    half8 bw1_10, bw1_11, bw1_12, bw1_13;
    half8 bw1_20, bw1_21, bw1_22, bw1_23;
    half8 bw2_00, bw2_01, bw2_02, bw2_03;
    half8 bw2_10, bw2_11, bw2_12, bw2_13;
    half8 bw2_20, bw2_21, bw2_22, bw2_23;
    half8 bw2_30, bw2_31, bw2_32, bw2_33;
    {
        #define LD1(c,g) *(const half8*)(pk1 + (((c * 16) + (w + 4 * g)) * 64 + lane) * 8)
        #define LD2(c,g) *(const half8*)(pk2 + (((c * 16) + (w + 4 * g)) * 64 + lane) * 8)
        bw1_00 = LD1(0,0); bw1_01 = LD1(0,1); bw1_02 = LD1(0,2); bw1_03 = LD1(0,3);
        bw1_10 = LD1(1,0); bw1_11 = LD1(1,1); bw1_12 = LD1(1,2); bw1_13 = LD1(1,3);
        bw1_20 = LD1(2,0); bw1_21 = LD1(2,1); bw1_22 = LD1(2,2); bw1_23 = LD1(2,3);
        bw2_00 = LD2(0,0); bw2_01 = LD2(0,1); bw2_02 = LD2(0,2); bw2_03 = LD2(0,3);
        bw2_10 = LD2(1,0); bw2_11 = LD2(1,1); bw2_12 = LD2(1,2); bw2_13 = LD2(1,3);
        bw2_20 = LD2(2,0); bw2_21 = LD2(2,1); bw2_22 = LD2(2,2); bw2_23 = LD2(2,3);
        bw2_30 = LD2(3,0); bw2_31 = LD2(3,1); bw2_32 = LD2(3,2); bw2_33 = LD2(3,3);
        #undef LD1
        #undef LD2
    }

    float bias1[4], bias2[4];
    #pragma unroll
    for (int g = 0; g < 4; ++g) {
        bias1[g] = bsum[(w + 4 * g) * 16 + l15];
        bias2[g] = bsum[256 + (w + 4 * g) * 16 + l15];
    }

    const int hpos = ((w >> 1) << 5) + 8 * (l15 >> 2) + (l15 & 3) + ((w & 1) << 2);

    f32x4 c1 = {0.f, 0.f, 0.f, 0.f};
    f32x4 c2 = {0.f, 0.f, 0.f, 0.f};

    // merged-reciprocal cell update: G = pre-scaled gates, cs = cell state,
    // hb = base of destination h buffer
    auto cell_update = [&](f32x4* G, f32x4& cs, _Float16* hb) {
        #pragma unroll
        for (int r = 0; r < 4; ++r) {
            float ei = __builtin_amdgcn_exp2f(G[0][r]);   // e^-xi
            float ef = __builtin_amdgcn_exp2f(G[1][r]);   // e^-xf
            float eg = __builtin_amdgcn_exp2f(G[2][r]);   // e^-2g
            float eo = __builtin_amdgcn_exp2f(G[3][r]);   // e^-xo
            float ai = 1.0f + ei, af = 1.0f + ef, ag = 1.0f + eg;
            float gm = 1.0f - eg;
            float pp = ai * ag;
            float num = __builtin_fmaf(gm, af, cs[r] * pp);
            float den = af * pp;
            float cc  = num * __builtin_amdgcn_rcpf(den);
            cs[r] = cc;
            float z  = cc * TWOL2E;
            int   zi = __float_as_int(z);
            float ec = __builtin_amdgcn_exp2f(__int_as_float(zi | (int)0x80000000)); // e^-2|c|
            float tm = 1.0f - ec;                          // >= 0
            float d2 = (1.0f + eo) * (1.0f + ec);
            float hs = __int_as_float(__float_as_int(tm) ^ (zi & (int)0x80000000));
            float hv = hs * __builtin_amdgcn_rcpf(d2);     // o * tanh(c)
            hb[(4 * l4 + r) * 72 + hpos] = (_Float16)hv;
        }
    };

    // ---- preloop: C = gates1(0) = b1 + Wx*x(0)  (h1(-1)=0)
    prefetch_x(0);
    f32x4 C[4];
    {
        half8 ax0 = build_ax();
        #pragma unroll
        for (int g = 0; g < 4; ++g) C[g] = (f32x4){bias1[g], bias1[g], bias1[g], bias1[g]};
        C[0] = __builtin_amdgcn_mfma_f32_16x16x32_f16(ax0, bw1_20, C[0], 0, 0, 0);
        C[1] = __builtin_amdgcn_mfma_f32_16x16x32_f16(ax0, bw1_21, C[1], 0, 0, 0);
        C[2] = __builtin_amdgcn_mfma_f32_16x16x32_f16(ax0, bw1_22, C[2], 0, 0, 0);
        C[3] = __builtin_amdgcn_mfma_f32_16x16x32_f16(ax0, bw1_23, C[3], 0, 0, 0);
    }
    prefetch_x(1);

    int p = 0;
    for (int t = 0; t < T_STEPS; ++t) {
        // pin weight frags + biases: loop-carried in regs, no remat
        asm volatile("" :
            "+v"(bw1_00), "+v"(bw1_01), "+v"(bw1_02), "+v"(bw1_03),
            "+v"(bw1_10), "+v"(bw1_11), "+v"(bw1_12), "+v"(bw1_13),
            "+v"(bw1_20), "+v"(bw1_21), "+v"(bw1_22), "+v"(bw1_23));
        asm volatile("" :
            "+v"(bw2_00), "+v"(bw2_01), "+v"(bw2_02), "+v"(bw2_03),
            "+v"(bw2_10), "+v"(bw2_11), "+v"(bw2_12), "+v"(bw2_13),
            "+v"(bw2_20), "+v"(bw2_21), "+v"(bw2_22), "+v"(bw2_23),
            "+v"(bw2_30), "+v"(bw2_31), "+v"(bw2_32), "+v"(bw2_33),
            "+v"(bias1[0]), "+v"(bias1[1]), "+v"(bias1[2]), "+v"(bias1[3]),
            "+v"(bias2[0]), "+v"(bias2[1]), "+v"(bias2[2]), "+v"(bias2[3]));

        // ---- 1. layer1 cell update: c1(t), h1(t) -> buf [1-p]
        cell_update(C, c1, &h1s[1 - p][0][0]);

        // ---- 2. the step's single barrier: h1(t) visible (h2(t-1) already)
        __syncthreads();

        // ---- 3. A-fragments
        half8 a10  = *(const half8*)&h1s[1 - p][l15][ 0 + 8 * l4];   // h1(t)
        half8 a11  = *(const half8*)&h1s[1 - p][l15][32 + 8 * l4];
        half8 a2h0 = *(const half8*)&h2s[p][l15][ 0 + 8 * l4];       // h2(t-1)
        half8 a2h1 = *(const half8*)&h2s[p][l15][32 + 8 * l4];
        half8 ax   = build_ax();                                      // x(t+1)
        int nt = t + 2; if (nt > T_STEPS - 1) nt = T_STEPS - 1;
        prefetch_x(nt);

        // ---- 4a. D = gates2(t)
        f32x4 D[4];
        #pragma unroll
        for (int g = 0; g < 4; ++g) D[g] = (f32x4){bias2[g], bias2[g], bias2[g], bias2[g]};
        D[0] = __builtin_amdgcn_mfma_f32_16x16x32_f16(a10,  bw2_00, D[0], 0, 0, 0);
        D[1] = __builtin_amdgcn_mfma_f32_16x16x32_f16(a10,  bw2_01, D[1], 0, 0, 0);
        D[2] = __builtin_amdgcn_mfma_f32_16x16x32_f16(a10,  bw2_02, D[2], 0, 0, 0);
        D[3] = __builtin_amdgcn_mfma_f32_16x16x32_f16(a10,  bw2_03, D[3], 0, 0, 0);
        D[0] = __builtin_amdgcn_mfma_f32_16x16x32_f16(a11,  bw2_10, D[0], 0, 0, 0);
        D[1] = __builtin_amdgcn_mfma_f32_16x16x32_f16(a11,  bw2_11, D[1], 0, 0, 0);
        D[2] = __builtin_amdgcn_mfma_f32_16x16x32_f16(a11,  bw2_12, D[2], 0, 0, 0);
        D[3] = __builtin_amdgcn_mfma_f32_16x16x32_f16(a11,  bw2_13, D[3], 0, 0, 0);
        D[0] = __builtin_amdgcn_mfma_f32_16x16x32_f16(a2h0, bw2_20, D[0], 0, 0, 0);
        D[1] = __builtin_amdgcn_mfma_f32_16x16x32_f16(a2h0, bw2_21, D[1], 0, 0, 0);
        D[2] = __builtin_amdgcn_mfma_f32_16x16x32_f16(a2h0, bw2_22, D[2], 0, 0, 0);
        D[3] = __builtin_amdgcn_mfma_f32_16x16x32_f16(a2h0, bw2_23, D[3], 0, 0, 0);
        D[0] = __builtin_amdgcn_mfma_f32_16x16x32_f16(a2h1, bw2_30, D[0], 0, 0, 0);
        D[1] = __builtin_amdgcn_mfma_f32_16x16x32_f16(a2h1, bw2_31, D[1], 0, 0, 0);
        D[2] = __builtin_amdgcn_mfma_f32_16x16x32_f16(a2h1, bw2_32, D[2], 0, 0, 0);
        D[3] = __builtin_amdgcn_mfma_f32_16x16x32_f16(a2h1, bw2_33, D[3], 0, 0, 0);

        // ---- 4b. C' = gates1(t+1)  (reuses a10/a11; independent of D)
        f32x4 Cn[4];
        #pragma unroll
        for (int g = 0; g < 4; ++g) Cn[g] = (f32x4){bias1[g], bias1[g], bias1[g], bias1[g]};
        Cn[0] = __builtin_amdgcn_mfma_f32_16x16x32_f16(a10, bw1_00, Cn[0], 0, 0, 0);
        Cn[1] = __builtin_amdgcn_mfma_f32_16x16x32_f16(a10, bw1_01, Cn[1], 0, 0, 0);
        Cn[2] = __builtin_amdgcn_mfma_f32_16x16x32_f16(a10, bw1_02, Cn[2], 0, 0, 0);
        Cn[3] = __builtin_amdgcn_mfma_f32_16x16x32_f16(a10, bw1_03, Cn[3], 0, 0, 0);
        Cn[0] = __builtin_amdgcn_mfma_f32_16x16x32_f16(a11, bw1_10, Cn[0], 0, 0, 0);
        Cn[1] = __builtin_amdgcn_mfma_f32_16x16x32_f16(a11, bw1_11, Cn[1], 0, 0, 0);
        Cn[2] = __builtin_amdgcn_mfma_f32_16x16x32_f16(a11, bw1_12, Cn[2], 0, 0, 0);
        Cn[3] = __builtin_amdgcn_mfma_f32_16x16x32_f16(a11, bw1_13, Cn[3], 0, 0, 0);
        Cn[0] = __builtin_amdgcn_mfma_f32_16x16x32_f16(ax,  bw1_20, Cn[0], 0, 0, 0);
        Cn[1] = __builtin_amdgcn_mfma_f32_16x16x32_f16(ax,  bw1_21, Cn[1], 0, 0, 0);
        Cn[2] = __builtin_amdgcn_mfma_f32_16x16x32_f16(ax,  bw1_22, Cn[2], 0, 0, 0);
        Cn[3] = __builtin_amdgcn_mfma_f32_16x16x32_f16(ax,  bw1_23, Cn[3], 0, 0, 0);

        // ---- 5. layer2 cell update: c2(t), h2(t) -> buf [1-p]
        cell_update(D, c2, &h2s[1 - p][0][0]);

        // ---- 6. advance
        #pragma unroll
        for (int g = 0; g < 4; ++g) C[g] = Cn[g];
        p ^= 1;
    }
    __syncthreads();   // final h2 writes visible to head

    // ---- output head: h2(199) in h2s[0] (iter 199 wrote [1-(199&1)] = [0])
    if (tid < 48) {
        int bl = tid / 3, o = tid - bl * 3;
        float acc = bout[o];
        #pragma unroll 8
        for (int pos = 0; pos < HDIM; ++pos) {
            int sub = pos & 31;
            int j = (pos >> 5) * 32 + (((sub >> 2) & 1) << 4) + ((sub >> 3) << 2) + (sub & 3);
            acc = __builtin_fmaf(Wout[o * 64 + j], (float)h2s[0][bl][pos], acc);
        }
        out[(bbase + bl) * 3 + o] = acc;
    }
}

extern "C" void kernel_launch(void* const* d_in, const int* in_sizes, int n_in,
                              void* d_out, int out_size, void* d_ws, size_t ws_size,
                              hipStream_t stream) {
    const float* x     = (const float*)d_in[0];
    const float* Wih1  = (const float*)d_in[1];
    const float* Whh1  = (const float*)d_in[2];
    const float* bih1  = (const float*)d_in[3];
    const float* bhh1  = (const float*)d_in[4];
    const float* Wih2  = (const float*)d_in[5];
    const float* Whh2  = (const float*)d_in[6];
    const float* bih2  = (const float*)d_in[7];
    const float* bhh2  = (const float*)d_in[8];
    const float* Wout  = (const float*)d_in[9];
    const float* bout  = (const float*)d_in[10];
    float* ws  = (float*)d_ws;
    float* out = (float*)d_out;

    pack_kernel<<<(PACK_TOT + 255) / 256, 256, 0, stream>>>(
        Wih1, Whh1, bih1, bhh1, Wih2, Whh2, bih2, bhh2, ws);

    lstm_mfma<<<B_TOT / 16, 256, 0, stream>>>(x, ws, Wout, bout, out);
}

// Round 8
// 526.372 us; speedup vs baseline: 1.5416x; 1.1349x over previous
//
#include <hip/hip_runtime.h>
#include <hip/hip_bf16.h>

// LSTM: B=16384, T=200, IN=9, H=64, OUT=3, 2 layers + linear head.
// Round 8: R7 host + (1) batched 4-way reciprocals (2 rcp/group, was 8),
//          (2) loop unroll x2 (no C copies, const LDS addrs),
//          (3) f16 x-window in LDS with 8-step-early global prefetch (T14).
// Block = 16 batches, 256 threads (4 waves). Grid = 1024 blocks.
// Wave w owns gate n-tiles {w, w+4, w+8, w+12}.
// Fragment layouts (gfx950 16x16x32, verified R2-R7):
//   A: lane l holds A[m=l&15][k=4*(l>>4)+(j&3)+16*(j>>2)]
//   B: lane l holds B[k=...][n=l&15]
//   C/D: col=l&15, row=(l>>4)*4+reg
// LDS h-state k-PERMUTED (R3). Weight pre-scale (R7): i,f,o x(-log2e), g x(-2log2e).
// x window: xwin[buf][s][quad l4][batch][4] f16; ax[j>=4] multiplies zero
// weights (k>=80) so we duplicate the low half (finite, never NaN).

#define B_TOT   16384
#define T_STEPS 200
#define IN_DIM  9
#define HDIM    64

#define PK1_OFF 0         // [3][16][64][8] = 24576 f16
#define PK2_OFF 24576     // [4][16][64][8] = 32768 f16
#define BSUM_HALF_OFF 57344   // then 512 f32 (b1[256], b2[256])
#define PACK_W_TOT 57344
#define PACK_TOT (PACK_W_TOT + 512)

#define L2E     1.44269504089f
#define TWOL2E  2.88539008178f

typedef _Float16 half8  __attribute__((ext_vector_type(8)));
typedef _Float16 half4v __attribute__((ext_vector_type(4)));
typedef float    f32x4  __attribute__((ext_vector_type(4)));
typedef float    f4u    __attribute__((ext_vector_type(4), aligned(4)));

// ---------------- prep: repack weights (B-frag layout, scales folded) -------
__global__ void pack_kernel(const float* __restrict__ Wih1, const float* __restrict__ Whh1,
                            const float* __restrict__ bih1, const float* __restrict__ bhh1,
                            const float* __restrict__ Wih2, const float* __restrict__ Whh2,
                            const float* __restrict__ bih2, const float* __restrict__ bhh2,
                            float* __restrict__ ws) {
    int e = blockIdx.x * 256 + threadIdx.x;
    if (e >= PACK_TOT) return;
    _Float16* wh = (_Float16*)ws;
    float* bptr = (float*)(wh + BSUM_HALF_OFF);
    auto gscale = [](int q) -> float {
        int gt = q >> 6;                       // 0=i,1=f,2=g,3=o
        return (gt == 2) ? (-2.0f * L2E) : -L2E;
    };
    if (e < PK2_OFF) {
        int j = e & 7, lane = (e >> 3) & 63, nt = (e >> 9) & 15, c = e >> 13;
        int k = c * 32 + 4 * (lane >> 4) + (j & 3) + 16 * (j >> 2);
        int q = nt * 16 + (lane & 15);
        float v = 0.0f;
        if (k < 64)      v = Whh1[q * 64 + k];
        else if (k < 73) v = Wih1[q * 9 + (k - 64)];
        wh[e] = (_Float16)(v * gscale(q));
    } else if (e < PACK_W_TOT) {
        int e2 = e - PK2_OFF;
        int j = e2 & 7, lane = (e2 >> 3) & 63, nt = (e2 >> 9) & 15, c = e2 >> 13;
        int k = c * 32 + 4 * (lane >> 4) + (j & 3) + 16 * (j >> 2);
        int q = nt * 16 + (lane & 15);
        float v = (k < 64) ? Wih2[q * 64 + k] : Whh2[q * 64 + (k - 64)];
        wh[e] = (_Float16)(v * gscale(q));
    } else if (e < PACK_W_TOT + 256) {
        int q = e - PACK_W_TOT;
        bptr[q] = (bih1[q] + bhh1[q]) * gscale(q);
    } else {
        int q = e - PACK_W_TOT - 256;
        bptr[256 + q] = (bih2[q] + bhh2[q]) * gscale(q);
    }
}

// ---------------- main sequential LSTM ----------------
__global__ __launch_bounds__(256, 2) void lstm_mfma(
    const float* __restrict__ x,
    const float* __restrict__ ws_f,
    const float* __restrict__ Wout,
    const float* __restrict__ bout,
    float* __restrict__ out)
{
    const int tid  = threadIdx.x;
    const int lane = tid & 63;
    const int w    = __builtin_amdgcn_readfirstlane(tid >> 6);   // 0..3
    const int l15  = lane & 15;
    const int l4   = lane >> 4;

    const _Float16* wh  = (const _Float16*)ws_f;
    const _Float16* pk1 = wh + PK1_OFF;
    const _Float16* pk2 = wh + PK2_OFF;
    const float* bsum   = (const float*)(wh + BSUM_HALF_OFF);

    __shared__ _Float16 h1s[2][16][72];
    __shared__ _Float16 h2s[2][16][72];
    __shared__ _Float16 xwin[2][8][4][16][4];   // [buf][step&7][quad][batch][4]

    for (int i = tid; i < 2 * 16 * 72; i += 256) {
        (&h1s[0][0][0])[i] = (_Float16)0.0f;
        (&h2s[0][0][0])[i] = (_Float16)0.0f;
    }
    for (int i = tid; i < 2 * 8 * 4 * 16 * 4; i += 256)
        (&xwin[0][0][0][0][0])[i] = (_Float16)0.0f;

    const int bbase = blockIdx.x * 16;

    // ---- x loader: thread handles batch b_=tid&15, entries pz=z_ and z_+16
    const int b_ = tid & 15, z_ = tid >> 4;
    const int s0_ = (z_ * 11) >> 5, q0_ = z_ - 3 * s0_;
    const bool act1 = (z_ < 8);                 // waves 0-1 only (wave-uniform)
    const int pz1 = z_ + 16;
    const int s1_ = (pz1 * 11) >> 5, q1_ = pz1 - 3 * s1_;
    const float* xbL = x + (long)(bbase + b_) * (T_STEPS * IN_DIM);

    f4u pfA = {0.f, 0.f, 0.f, 0.f}, pfB = {0.f, 0.f, 0.f, 0.f};
    auto fetch_x = [&](int wb) {                // issue global loads (early)
        int t0 = wb + s0_; if (t0 > T_STEPS - 1) t0 = T_STEPS - 1;
        const float* p0 = xbL + t0 * IN_DIM + 4 * q0_;
        if (q0_ < 2) pfA = *(const f4u*)p0; else pfA[0] = p0[0];
        if (act1) {
            int t1 = wb + s1_; if (t1 > T_STEPS - 1) t1 = T_STEPS - 1;
            const float* p1 = xbL + t1 * IN_DIM + 4 * q1_;
            if (q1_ < 2) pfB = *(const f4u*)p1; else pfB[0] = p1[0];
        }
    };
    auto store_x = [&](int buf) {               // cvt + LDS write (late)
        f4u A = pfA, B = pfB;
        if (q0_ == 2) { A[1] = 0.f; A[2] = 0.f; A[3] = 0.f; }
        half4v hv;
        hv[0] = (_Float16)A[0]; hv[1] = (_Float16)A[1];
        hv[2] = (_Float16)A[2]; hv[3] = (_Float16)A[3];
        *(half4v*)&xwin[buf][s0_][q0_][b_][0] = hv;
        if (act1) {
            if (q1_ == 2) { B[1] = 0.f; B[2] = 0.f; B[3] = 0.f; }
            half4v hw;
            hw[0] = (_Float16)B[0]; hw[1] = (_Float16)B[1];
            hw[2] = (_Float16)B[2]; hw[3] = (_Float16)B[3];
            *(half4v*)&xwin[buf][s1_][q1_][b_][0] = hw;
        }
    };
    auto read_ax = [&](int tt) -> half8 {       // A-frag for x(tt)
        half4v xq = *(const half4v*)&xwin[(tt >> 3) & 1][tt & 7][l4][l15][0];
        return __builtin_shufflevector(xq, xq, 0, 1, 2, 3, 0, 1, 2, 3);
    };

    // ---- weight B-fragments: 28 x half8, loop-pinned
    half8 bw1_00, bw1_01, bw1_02, bw1_03;
    half8 bw1_10, bw1_11, bw1_12, bw1_13;
    half8 bw1_20, bw1_21, bw1_22, bw1_23;
    half8 bw2_00, bw2_01, bw2_02, bw2_03;
    half8 bw2_10, bw2_11, bw2_12, bw2_13;
    half8 bw2_20, bw2_21, bw2_22, bw2_23;
    half8 bw2_30, bw2_31, bw2_32, bw2_33;
    {
        #define LD1(c,g) *(const half8*)(pk1 + (((c * 16) + (w + 4 * g)) * 64 + lane) * 8)
        #define LD2(c,g) *(const half8*)(pk2 + (((c * 16) + (w + 4 * g)) * 64 + lane) * 8)
        bw1_00 = LD1(0,0); bw1_01 = LD1(0,1); bw1_02 = LD1(0,2); bw1_03 = LD1(0,3);
        bw1_10 = LD1(1,0); bw1_11 = LD1(1,1); bw1_12 = LD1(1,2); bw1_13 = LD1(1,3);
        bw1_20 = LD1(2,0); bw1_21 = LD1(2,1); bw1_22 = LD1(2,2); bw1_23 = LD1(2,3);
        bw2_00 = LD2(0,0); bw2_01 = LD2(0,1); bw2_02 = LD2(0,2); bw2_03 = LD2(0,3);
        bw2_10 = LD2(1,0); bw2_11 = LD2(1,1); bw2_12 = LD2(1,2); bw2_13 = LD2(1,3);
        bw2_20 = LD2(2,0); bw2_21 = LD2(2,1); bw2_22 = LD2(2,2); bw2_23 = LD2(2,3);
        bw2_30 = LD2(3,0); bw2_31 = LD2(3,1); bw2_32 = LD2(3,2); bw2_33 = LD2(3,3);
        #undef LD1
        #undef LD2
    }

    float bias1[4], bias2[4];
    #pragma unroll
    for (int g = 0; g < 4; ++g) {
        bias1[g] = bsum[(w + 4 * g) * 16 + l15];
        bias2[g] = bsum[256 + (w + 4 * g) * 16 + l15];
    }

    const int hpos = ((w >> 1) << 5) + 8 * (l15 >> 2) + (l15 & 3) + ((w & 1) << 2);

    f32x4 c1 = {0.f, 0.f, 0.f, 0.f};
    f32x4 c2 = {0.f, 0.f, 0.f, 0.f};

    // merged cell update: batched 4-way reciprocals (2 rcp, was 8)
    auto cell_update = [&](f32x4* G, f32x4& cs, _Float16* hb) {
        float num[4], den[4], eo4[4], d2[4], hs4[4];
        #pragma unroll
        for (int r = 0; r < 4; ++r) {
            float ei = __builtin_amdgcn_exp2f(G[0][r]);   // e^-xi
            float ef = __builtin_amdgcn_exp2f(G[1][r]);   // e^-xf
            float eg = __builtin_amdgcn_exp2f(G[2][r]);   // e^-2g
            eo4[r]   = __builtin_amdgcn_exp2f(G[3][r]);   // e^-xo
            float ai = 1.0f + ei, af = 1.0f + ef, ag = 1.0f + eg;
            float gm = 1.0f - eg;
            float pp = ai * ag;
            num[r] = __builtin_fmaf(gm, af, cs[r] * pp);
            den[r] = af * pp;
        }
        float s01 = den[0] * den[1], s23 = den[2] * den[3];
        float Pinv = __builtin_amdgcn_rcpf(s01 * s23);
        float r01 = Pinv * s23, r23 = Pinv * s01;
        float inv0 = r01 * den[1], inv1 = r01 * den[0];
        float inv2 = r23 * den[3], inv3 = r23 * den[2];
        float inv[4] = {inv0, inv1, inv2, inv3};
        #pragma unroll
        for (int r = 0; r < 4; ++r) {
            float cc = num[r] * inv[r];
            cs[r] = cc;
            float z  = cc * TWOL2E;
            int   zi = __float_as_int(z);
            float ec = __builtin_amdgcn_exp2f(__int_as_float(zi | (int)0x80000000)); // 2^-|z|
            float tm = 1.0f - ec;
            d2[r] = (1.0f + eo4[r]) * (1.0f + ec);
            hs4[r] = __int_as_float(__float_as_int(tm) ^ (zi & (int)0x80000000));
        }
        float t01 = d2[0] * d2[1], t23 = d2[2] * d2[3];
        float Qinv = __builtin_amdgcn_rcpf(t01 * t23);
        float q01 = Qinv * t23, q23 = Qinv * t01;
        float jnv[4] = {q01 * d2[1], q01 * d2[0], q23 * d2[3], q23 * d2[2]};
        #pragma unroll
        for (int r = 0; r < 4; ++r)
            hb[(4 * l4 + r) * 72 + hpos] = (_Float16)(hs4[r] * jnv[r]);
    };

    #define PIN_ALL() do {                                                      \
        asm volatile("" :                                                       \
            "+v"(bw1_00), "+v"(bw1_01), "+v"(bw1_02), "+v"(bw1_03),             \
            "+v"(bw1_10), "+v"(bw1_11), "+v"(bw1_12), "+v"(bw1_13),             \
            "+v"(bw1_20), "+v"(bw1_21), "+v"(bw1_22), "+v"(bw1_23));            \
        asm volatile("" :                                                       \
            "+v"(bw2_00), "+v"(bw2_01), "+v"(bw2_02), "+v"(bw2_03),             \
            "+v"(bw2_10), "+v"(bw2_11), "+v"(bw2_12), "+v"(bw2_13),             \
            "+v"(bw2_20), "+v"(bw2_21), "+v"(bw2_22), "+v"(bw2_23),             \
            "+v"(bw2_30), "+v"(bw2_31), "+v"(bw2_32), "+v"(bw2_33),             \
            "+v"(bias1[0]), "+v"(bias1[1]), "+v"(bias1[2]), "+v"(bias1[3]),     \
            "+v"(bias2[0]), "+v"(bias2[1]), "+v"(bias2[2]), "+v"(bias2[3]));    \
    } while (0)

    // ---- preloop: fill x window 0, prefetch window 1, init C = gates1(0)
    fetch_x(0);
    __syncthreads();              // LDS zeros committed (before store_x writes)
    store_x(0);                   // buf0 = x(0..7)
    fetch_x(8);                   // regs = x(8..15), stored at t=0
    __syncthreads();              // window 0 + zero h state visible

    f32x4 C[4];
    {
        half8 ax0 = read_ax(0);
        #pragma unroll
        for (int g = 0; g < 4; ++g) C[g] = (f32x4){bias1[g], bias1[g], bias1[g], bias1[g]};
        C[0] = __builtin_amdgcn_mfma_f32_16x16x32_f16(ax0, bw1_20, C[0], 0, 0, 0);
        C[1] = __builtin_amdgcn_mfma_f32_16x16x32_f16(ax0, bw1_21, C[1], 0, 0, 0);
        C[2] = __builtin_amdgcn_mfma_f32_16x16x32_f16(ax0, bw1_22, C[2], 0, 0, 0);
        C[3] = __builtin_amdgcn_mfma_f32_16x16x32_f16(ax0, bw1_23, C[3], 0, 0, 0);
    }

    for (int t = 0; t < T_STEPS; t += 2) {
        // ================= body A (even t): writes h buf[1], reads h2 buf[0]
        PIN_ALL();
        cell_update(C, c1, &h1s[1][0][0]);
        if ((t & 7) == 0) {                   // window rotate (every 8 steps)
            store_x(((t >> 3) + 1) & 1);      // commit x(t+8..t+15)
            fetch_x(t + 16);                  // issue loads for x(t+16..t+23)
        }
        __syncthreads();                      // h1(t) visible

        half8 a10  = *(const half8*)&h1s[1][l15][ 0 + 8 * l4];
        half8 a11  = *(const half8*)&h1s[1][l15][32 + 8 * l4];
        half8 a2h0 = *(const half8*)&h2s[0][l15][ 0 + 8 * l4];
        half8 a2h1 = *(const half8*)&h2s[0][l15][32 + 8 * l4];
        half8 ax   = read_ax(t + 1);

        f32x4 D[4];
        #pragma unroll
        for (int g = 0; g < 4; ++g) D[g] = (f32x4){bias2[g], bias2[g], bias2[g], bias2[g]};
        D[0] = __builtin_amdgcn_mfma_f32_16x16x32_f16(a10,  bw2_00, D[0], 0, 0, 0);
        D[1] = __builtin_amdgcn_mfma_f32_16x16x32_f16(a10,  bw2_01, D[1], 0, 0, 0);
        D[2] = __builtin_amdgcn_mfma_f32_16x16x32_f16(a10,  bw2_02, D[2], 0, 0, 0);
        D[3] = __builtin_amdgcn_mfma_f32_16x16x32_f16(a10,  bw2_03, D[3], 0, 0, 0);
        D[0] = __builtin_amdgcn_mfma_f32_16x16x32_f16(a11,  bw2_10, D[0], 0, 0, 0);
        D[1] = __builtin_amdgcn_mfma_f32_16x16x32_f16(a11,  bw2_11, D[1], 0, 0, 0);
        D[2] = __builtin_amdgcn_mfma_f32_16x16x32_f16(a11,  bw2_12, D[2], 0, 0, 0);
        D[3] = __builtin_amdgcn_mfma_f32_16x16x32_f16(a11,  bw2_13, D[3], 0, 0, 0);
        D[0] = __builtin_amdgcn_mfma_f32_16x16x32_f16(a2h0, bw2_20, D[0], 0, 0, 0);
        D[1] = __builtin_amdgcn_mfma_f32_16x16x32_f16(a2h0, bw2_21, D[1], 0, 0, 0);
        D[2] = __builtin_amdgcn_mfma_f32_16x16x32_f16(a2h0, bw2_22, D[2], 0, 0, 0);
        D[3] = __builtin_amdgcn_mfma_f32_16x16x32_f16(a2h0, bw2_23, D[3], 0, 0, 0);
        D[0] = __builtin_amdgcn_mfma_f32_16x16x32_f16(a2h1, bw2_30, D[0], 0, 0, 0);
        D[1] = __builtin_amdgcn_mfma_f32_16x16x32_f16(a2h1, bw2_31, D[1], 0, 0, 0);
        D[2] = __builtin_amdgcn_mfma_f32_16x16x32_f16(a2h1, bw2_32, D[2], 0, 0, 0);
        D[3] = __builtin_amdgcn_mfma_f32_16x16x32_f16(a2h1, bw2_33, D[3], 0, 0, 0);

        f32x4 CB[4];
        #pragma unroll
        for (int g = 0; g < 4; ++g) CB[g] = (f32x4){bias1[g], bias1[g], bias1[g], bias1[g]};
        CB[0] = __builtin_amdgcn_mfma_f32_16x16x32_f16(a10, bw1_00, CB[0], 0, 0, 0);
        CB[1] = __builtin_amdgcn_mfma_f32_16x16x32_f16(a10, bw1_01, CB[1], 0, 0, 0);
        CB[2] = __builtin_amdgcn_mfma_f32_16x16x32_f16(a10, bw1_02, CB[2], 0, 0, 0);
        CB[3] = __builtin_amdgcn_mfma_f32_16x16x32_f16(a10, bw1_03, CB[3], 0, 0, 0);
        CB[0] = __builtin_amdgcn_mfma_f32_16x16x32_f16(a11, bw1_10, CB[0], 0, 0, 0);
        CB[1] = __builtin_amdgcn_mfma_f32_16x16x32_f16(a11, bw1_11, CB[1], 0, 0, 0);
        CB[2] = __builtin_amdgcn_mfma_f32_16x16x32_f16(a11, bw1_12, CB[2], 0, 0, 0);
        CB[3] = __builtin_amdgcn_mfma_f32_16x16x32_f16(a11, bw1_13, CB[3], 0, 0, 0);
        CB[0] = __builtin_amdgcn_mfma_f32_16x16x32_f16(ax,  bw1_20, CB[0], 0, 0, 0);
        CB[1] = __builtin_amdgcn_mfma_f32_16x16x32_f16(ax,  bw1_21, CB[1], 0, 0, 0);
        CB[2] = __builtin_amdgcn_mfma_f32_16x16x32_f16(ax,  bw1_22, CB[2], 0, 0, 0);
        CB[3] = __builtin_amdgcn_mfma_f32_16x16x32_f16(ax,  bw1_23, CB[3], 0, 0, 0);

        cell_update(D, c2, &h2s[1][0][0]);

        // ================= body B (odd t+1): writes h buf[0], reads h2 buf[1]
        PIN_ALL();
        cell_update(CB, c1, &h1s[0][0][0]);
        __syncthreads();                      // h1(t+1) visible

        half8 b10  = *(const half8*)&h1s[0][l15][ 0 + 8 * l4];
        half8 b11  = *(const half8*)&h1s[0][l15][32 + 8 * l4];
        half8 b2h0 = *(const half8*)&h2s[1][l15][ 0 + 8 * l4];
        half8 b2h1 = *(const half8*)&h2s[1][l15][32 + 8 * l4];
        half8 bx   = read_ax(t + 2);

        f32x4 E[4];
        #pragma unroll
        for (int g = 0; g < 4; ++g) E[g] = (f32x4){bias2[g], bias2[g], bias2[g], bias2[g]};
        E[0] = __builtin_amdgcn_mfma_f32_16x16x32_f16(b10,  bw2_00, E[0], 0, 0, 0);
        E[1] = __builtin_amdgcn_mfma_f32_16x16x32_f16(b10,  bw2_01, E[1], 0, 0, 0);
        E[2] = __builtin_amdgcn_mfma_f32_16x16x32_f16(b10,  bw2_02, E[2], 0, 0, 0);
        E[3] = __builtin_amdgcn_mfma_f32_16x16x32_f16(b10,  bw2_03, E[3], 0, 0, 0);
        E[0] = __builtin_amdgcn_mfma_f32_16x16x32_f16(b11,  bw2_10, E[0], 0, 0, 0);
        E[1] = __builtin_amdgcn_mfma_f32_16x16x32_f16(b11,  bw2_11, E[1], 0, 0, 0);
        E[2] = __builtin_amdgcn_mfma_f32_16x16x32_f16(b11,  bw2_12, E[2], 0, 0, 0);
        E[3] = __builtin_amdgcn_mfma_f32_16x16x32_f16(b11,  bw2_13, E[3], 0, 0, 0);
        E[0] = __builtin_amdgcn_mfma_f32_16x16x32_f16(b2h0, bw2_20, E[0], 0, 0, 0);
        E[1] = __builtin_amdgcn_mfma_f32_16x16x32_f16(b2h0, bw2_21, E[1], 0, 0, 0);
        E[2] = __builtin_amdgcn_mfma_f32_16x16x32_f16(b2h0, bw2_22, E[2], 0, 0, 0);
        E[3] = __builtin_amdgcn_mfma_f32_16x16x32_f16(b2h0, bw2_23, E[3], 0, 0, 0);
        E[0] = __builtin_amdgcn_mfma_f32_16x16x32_f16(b2h1, bw2_30, E[0], 0, 0, 0);
        E[1] = __builtin_amdgcn_mfma_f32_16x16x32_f16(b2h1, bw2_31, E[1], 0, 0, 0);
        E[2] = __builtin_amdgcn_mfma_f32_16x16x32_f16(b2h1, bw2_32, E[2], 0, 0, 0);
        E[3] = __builtin_amdgcn_mfma_f32_16x16x32_f16(b2h1, bw2_33, E[3], 0, 0, 0);

        #pragma unroll
        for (int g = 0; g < 4; ++g) C[g] = (f32x4){bias1[g], bias1[g], bias1[g], bias1[g]};
        C[0] = __builtin_amdgcn_mfma_f32_16x16x32_f16(b10, bw1_00, C[0], 0, 0, 0);
        C[1] = __builtin_amdgcn_mfma_f32_16x16x32_f16(b10, bw1_01, C[1], 0, 0, 0);
        C[2] = __builtin_amdgcn_mfma_f32_16x16x32_f16(b10, bw1_02, C[2], 0, 0, 0);
        C[3] = __builtin_amdgcn_mfma_f32_16x16x32_f16(b10, bw1_03, C[3], 0, 0, 0);
        C[0] = __builtin_amdgcn_mfma_f32_16x16x32_f16(b11, bw1_10, C[0], 0, 0, 0);
        C[1] = __builtin_amdgcn_mfma_f32_16x16x32_f16(b11, bw1_11, C[1], 0, 0, 0);
        C[2] = __builtin_amdgcn_mfma_f32_16x16x32_f16(b11, bw1_12, C[2], 0, 0, 0);
        C[3] = __builtin_amdgcn_mfma_f32_16x16x32_f16(b11, bw1_13, C[3], 0, 0, 0);
        C[0] = __builtin_amdgcn_mfma_f32_16x16x32_f16(bx,  bw1_20, C[0], 0, 0, 0);
        C[1] = __builtin_amdgcn_mfma_f32_16x16x32_f16(bx,  bw1_21, C[1], 0, 0, 0);
        C[2] = __builtin_amdgcn_mfma_f32_16x16x32_f16(bx,  bw1_22, C[2], 0, 0, 0);
        C[3] = __builtin_amdgcn_mfma_f32_16x16x32_f16(bx,  bw1_23, C[3], 0, 0, 0);

        cell_update(E, c2, &h2s[0][0][0]);
    }
    __syncthreads();   // final h2 writes visible

    // ---- output head: h2(199) in h2s[0] (perm-stored)
    if (tid < 48) {
        int bl = tid / 3, o = tid - bl * 3;
        float acc = bout[o];
        #pragma unroll 8
        for (int pos = 0; pos < HDIM; ++pos) {
            int sub = pos & 31;
            int j = (pos >> 5) * 32 + (((sub >> 2) & 1) << 4) + ((sub >> 3) << 2) + (sub & 3);
            acc = __builtin_fmaf(Wout[o * 64 + j], (float)h2s[0][bl][pos], acc);
        }
        out[(bbase + bl) * 3 + o] = acc;
    }
    #undef PIN_ALL
}

extern "C" void kernel_launch(void* const* d_in, const int* in_sizes, int n_in,
                              void* d_out, int out_size, void* d_ws, size_t ws_size,
                              hipStream_t stream) {
    const float* x     = (const float*)d_in[0];
    const float* Wih1  = (const float*)d_in[1];
    const float* Whh1  = (const float*)d_in[2];
    const float* bih1  = (const float*)d_in[3];
    const float* bhh1  = (const float*)d_in[4];
    const float* Wih2  = (const float*)d_in[5];
    const float* Whh2  = (const float*)d_in[6];
    const float* bih2  = (const float*)d_in[7];
    const float* bhh2  = (const float*)d_in[8];
    const float* Wout  = (const float*)d_in[9];
    const float* bout  = (const float*)d_in[10];
    float* ws  = (float*)d_ws;
    float* out = (float*)d_out;

    pack_kernel<<<(PACK_TOT + 255) / 256, 256, 0, stream>>>(
        Wih1, Whh1, bih1, bhh1, Wih2, Whh2, bih2, bhh2, ws);

    lstm_mfma<<<B_TOT / 16, 256, 0, stream>>>(x, ws, Wout, bout, out);
}